// Round 9
// baseline (180.972 us; speedup 1.0000x reference)
//
#include <hip/hip_runtime.h>

// BEV pooling, single-kernel atomic formulation.
// out[bin,c] = sum_{i: rb[i]==bin} depth[rd[i]] * feat[rf[i], c],  rb SORTED.
// R9: the 2-phase (seg table) structure pays ~20us for the small kernel +
// extra dispatch. Fuse: partition by POINTS. Each wave owns 32 consecutive
// points, gathers both 16-point rows with ALL loads in flight at once (single
// latency exposure), scales by depth, then iterates the few sorted bin-runs in
// its window: masked xor-butterfly over 16 slots + HW fp32 atomics into out.
// out zeroed via hipMemsetAsync (graph-capturable). No d_ws, no seg kernel.

#define CHN 80
#define WPTS 32      // points per wave (16 slots x 2 rows)

__device__ __forceinline__ void sc4(float4& p, float d) {
    p.x *= d; p.y *= d; p.z *= d; p.w *= d;
}

__global__ __launch_bounds__(256)
void bev_pool_atomic_kernel(const float* __restrict__ depth,
                            const float* __restrict__ feat,
                            const int* __restrict__ rd,
                            const int* __restrict__ rf,
                            const int* __restrict__ rb,
                            float* __restrict__ out,
                            int P) {
    const int wave = threadIdx.x >> 6;
    const int lane = threadIdx.x & 63;
    const int gw = blockIdx.x * 4 + wave;            // global wave id
    const int w0 = gw * WPTS;
    if (w0 >= P) return;

    const int slot = lane >> 2;                      // 0..15
    const int ll   = lane & 3;                       // 0..3

    const int i1 = w0 + slot;                        // row 1: points w0..w0+15
    const int i2 = i1 + 16;                          // row 2: points w0+16..w0+31
    const bool v1 = i1 < P;
    const bool v2 = i2 < P;

    // ---- all index loads issue together ----
    int b1 = 0x7fffffff, b2 = 0x7fffffff;
    int di1 = 0, fi1 = 0, di2 = 0, fi2 = 0;
    if (v1) { b1 = rb[i1]; di1 = rd[i1]; fi1 = rf[i1]; }
    if (v2) { b2 = rb[i2]; di2 = rd[i2]; fi2 = rf[i2]; }

    // ---- all data loads issue together (single latency exposure) ----
    float d1 = 0.f, d2 = 0.f;
    float4 z4 = make_float4(0.f, 0.f, 0.f, 0.f);
    float4 p10 = z4, p11 = z4, p12 = z4, p13 = z4, p14 = z4;
    float4 p20 = z4, p21 = z4, p22 = z4, p23 = z4, p24 = z4;
    if (v1) {
        d1 = depth[di1];
        const float4* r = reinterpret_cast<const float4*>(feat + (size_t)fi1 * CHN) + ll;
        p10 = r[0]; p11 = r[4]; p12 = r[8]; p13 = r[12]; p14 = r[16];
    }
    if (v2) {
        d2 = depth[di2];
        const float4* r = reinterpret_cast<const float4*>(feat + (size_t)fi2 * CHN) + ll;
        p20 = r[0]; p21 = r[4]; p22 = r[8]; p23 = r[12]; p24 = r[16];
    }
    sc4(p10, d1); sc4(p11, d1); sc4(p12, d1); sc4(p13, d1); sc4(p14, d1);
    sc4(p20, d2); sc4(p21, d2); sc4(p22, d2); sc4(p23, d2); sc4(p24, d2);

    // ---- iterate sorted bin-runs within the 32-point window ----
    int cur = __shfl(b1, 0, 64);                     // smallest bin (lane 0, sorted)
    while (true) {
        const bool m1 = (b1 == cur);
        const bool m2 = (b2 == cur);
        float4 t0, t1, t2, t3, t4;
        t0.x = (m1 ? p10.x : 0.f) + (m2 ? p20.x : 0.f);
        t0.y = (m1 ? p10.y : 0.f) + (m2 ? p20.y : 0.f);
        t0.z = (m1 ? p10.z : 0.f) + (m2 ? p20.z : 0.f);
        t0.w = (m1 ? p10.w : 0.f) + (m2 ? p20.w : 0.f);
        t1.x = (m1 ? p11.x : 0.f) + (m2 ? p21.x : 0.f);
        t1.y = (m1 ? p11.y : 0.f) + (m2 ? p21.y : 0.f);
        t1.z = (m1 ? p11.z : 0.f) + (m2 ? p21.z : 0.f);
        t1.w = (m1 ? p11.w : 0.f) + (m2 ? p21.w : 0.f);
        t2.x = (m1 ? p12.x : 0.f) + (m2 ? p22.x : 0.f);
        t2.y = (m1 ? p12.y : 0.f) + (m2 ? p22.y : 0.f);
        t2.z = (m1 ? p12.z : 0.f) + (m2 ? p22.z : 0.f);
        t2.w = (m1 ? p12.w : 0.f) + (m2 ? p22.w : 0.f);
        t3.x = (m1 ? p13.x : 0.f) + (m2 ? p23.x : 0.f);
        t3.y = (m1 ? p13.y : 0.f) + (m2 ? p23.y : 0.f);
        t3.z = (m1 ? p13.z : 0.f) + (m2 ? p23.z : 0.f);
        t3.w = (m1 ? p13.w : 0.f) + (m2 ? p23.w : 0.f);
        t4.x = (m1 ? p14.x : 0.f) + (m2 ? p24.x : 0.f);
        t4.y = (m1 ? p14.y : 0.f) + (m2 ? p24.y : 0.f);
        t4.z = (m1 ? p14.z : 0.f) + (m2 ? p24.z : 0.f);
        t4.w = (m1 ? p14.w : 0.f) + (m2 ? p24.w : 0.f);

        // butterfly across the 16 slots (lane bits 2..5)
#pragma unroll
        for (int ofs = 4; ofs <= 32; ofs <<= 1) {
            t0.x += __shfl_xor(t0.x, ofs, 64); t0.y += __shfl_xor(t0.y, ofs, 64);
            t0.z += __shfl_xor(t0.z, ofs, 64); t0.w += __shfl_xor(t0.w, ofs, 64);
            t1.x += __shfl_xor(t1.x, ofs, 64); t1.y += __shfl_xor(t1.y, ofs, 64);
            t1.z += __shfl_xor(t1.z, ofs, 64); t1.w += __shfl_xor(t1.w, ofs, 64);
            t2.x += __shfl_xor(t2.x, ofs, 64); t2.y += __shfl_xor(t2.y, ofs, 64);
            t2.z += __shfl_xor(t2.z, ofs, 64); t2.w += __shfl_xor(t2.w, ofs, 64);
            t3.x += __shfl_xor(t3.x, ofs, 64); t3.y += __shfl_xor(t3.y, ofs, 64);
            t3.z += __shfl_xor(t3.z, ofs, 64); t3.w += __shfl_xor(t3.w, ofs, 64);
            t4.x += __shfl_xor(t4.x, ofs, 64); t4.y += __shfl_xor(t4.y, ofs, 64);
            t4.z += __shfl_xor(t4.z, ofs, 64); t4.w += __shfl_xor(t4.w, ofs, 64);
        }

        // lane L (<20) owns chunk L: channels [L*4, L*4+4), value t[L>>2]
        if (lane < 20) {
            const int j = lane >> 2;
            float4 w = t0;
            if (j == 1) w = t1;
            else if (j == 2) w = t2;
            else if (j == 3) w = t3;
            else if (j == 4) w = t4;
            float* dst = out + (size_t)cur * CHN + lane * 4;
            unsafeAtomicAdd(dst + 0, w.x);
            unsafeAtomicAdd(dst + 1, w.y);
            unsafeAtomicAdd(dst + 2, w.z);
            unsafeAtomicAdd(dst + 3, w.w);
        }

        // next run: wave-min over bins > cur
        int cand = 0x7fffffff;
        if (b1 > cur) cand = b1;
        if (b2 > cur && b2 < cand) cand = b2;
#pragma unroll
        for (int ofs = 1; ofs <= 32; ofs <<= 1) {
            const int o = __shfl_xor(cand, ofs, 64);
            cand = o < cand ? o : cand;
        }
        if (cand == 0x7fffffff) break;
        cur = cand;
    }
}

extern "C" void kernel_launch(void* const* d_in, const int* in_sizes, int n_in,
                              void* d_out, int out_size, void* d_ws, size_t ws_size,
                              hipStream_t stream) {
    const float* depth = (const float*)d_in[0];
    const float* feat  = (const float*)d_in[1];
    const int*   rd    = (const int*)d_in[2];
    const int*   rf    = (const int*)d_in[3];
    const int*   rb    = (const int*)d_in[4];
    // d_in[5], d_in[6] (interval_starts/lengths) unused per reference.
    float* out = (float*)d_out;

    const int P = in_sizes[2];

    hipMemsetAsync(out, 0, (size_t)out_size * sizeof(float), stream);

    const int waves = (P + WPTS - 1) / WPTS;
    const int blocks = (waves + 3) / 4;
    bev_pool_atomic_kernel<<<blocks, 256, 0, stream>>>(depth, feat, rd, rf, rb, out, P);
}